// Round 4
// baseline (741.840 us; speedup 1.0000x reference)
//
#include <hip/hip_runtime.h>
#include <math.h>
#include <stdint.h>

#define BB 1024
#define SS 200
#define HH 128
#define NI 100000

// Constant-address-space cast (CK idiom): forces s_load selection for
// wave-uniform reads -> Ur streams through the scalar K$ pipe, not LDS/VMEM.
#define AS4 __attribute__((address_space(4)))
typedef const AS4 float cfloat;
__device__ __forceinline__ cfloat* to_const_as(const float* p) {
    return (cfloat*)(uintptr_t)p;
}

// tanh(x) = sign(x) * (1 - e^{-2|x|}) / (1 + e^{-2|x|})
__device__ __forceinline__ float fast_tanh(float x) {
    float ax = fabsf(x);
    float t = __expf(-2.0f * ax);
    float r = (1.0f - t) / (1.0f + t);
    return copysignf(r, x);
}

// 32 individually-named float4 registers for the A row (NO array -> no scratch)
#define A_DECL(i) float4 A##i;
#define A_LOAD(i) A##i = arow[i];
#define FOR32(M) \
    M(0)  M(1)  M(2)  M(3)  M(4)  M(5)  M(6)  M(7)  \
    M(8)  M(9)  M(10) M(11) M(12) M(13) M(14) M(15) \
    M(16) M(17) M(18) M(19) M(20) M(21) M(22) M(23) \
    M(24) M(25) M(26) M(27) M(28) M(29) M(30) M(31)

// one float4-FMA step against scalar-path Ur: c += A_i * urow[4i..4i+3]
#define KSTEP(i, c) { \
    c.x = fmaf(A##i.x, urow[4*(i)+0], c.x); \
    c.y = fmaf(A##i.y, urow[4*(i)+1], c.y); \
    c.z = fmaf(A##i.z, urow[4*(i)+2], c.z); \
    c.w = fmaf(A##i.w, urow[4*(i)+3], c.w); }

__global__ __launch_bounds__(256, 2)
void rrd_fused_kernel(const float* __restrict__ allm,      // [B,S,H]
                      const float* __restrict__ lastm,     // [B,H]
                      const int* __restrict__ item_seq,    // [B,S]
                      const unsigned char* __restrict__ mask, // [B,S] bool
                      const float* __restrict__ Ur,        // [H,H]
                      const float* __restrict__ Wr,        // [H,H]
                      const float* __restrict__ Vr,        // [1,H]
                      const float* __restrict__ Vrb,       // [1]
                      float* __restrict__ out) {           // [B,N]
    const int b = blockIdx.x;
    const int tid = threadIdx.x;
    const int lane = tid & 63;
    const int wv = tid >> 6;
    const int s = tid;   // one seq position per thread; s >= SS lanes are helpers

    __shared__ float s_last[HH];
    __shared__ float s_lm[HH];
    __shared__ float s_red[8];

    // ---- 1. issue A-row loads FIRST (oldest vmem ops; usable before the
    //         fill stores are even issued) ----
    const float4* arow = reinterpret_cast<const float4*>(
        allm + ((size_t)b * SS + (s < SS ? s : 0)) * HH);
    FOR32(A_DECL)
    FOR32(A_LOAD)

    if (tid < HH) s_last[tid] = lastm[b * HH + tid];
    __syncthreads();

    // ---- 2. lm[k] = sum_h last[b,h] * Wr[k,h] ----
    if (tid < HH) {
        const float4* wrow = reinterpret_cast<const float4*>(Wr + tid * HH);
        const float4* lrow = reinterpret_cast<const float4*>(s_last);
        float4 acc = make_float4(0.f, 0.f, 0.f, 0.f);
        #pragma unroll
        for (int i = 0; i < HH / 4; ++i) {
            float4 w = wrow[i];
            float4 l = lrow[i];
            acc.x = fmaf(l.x, w.x, acc.x);
            acc.y = fmaf(l.y, w.y, acc.y);
            acc.z = fmaf(l.z, w.z, acc.z);
            acc.w = fmaf(l.w, w.w, acc.w);
        }
        s_lm[tid] = (acc.x + acc.y) + (acc.z + acc.w);
    }
    __syncthreads();

    // ---- 3. zero this batch's output row (fire-and-forget stores; they
    //         drain into L2 during the k-loop, HBM writeback in background)
    {
        float4* orow = reinterpret_cast<float4*>(out + (size_t)b * NI);
        const float4 z4 = make_float4(0.f, 0.f, 0.f, 0.f);
        for (int i = tid; i < NI / 4; i += 256) orow[i] = z4;
    }

    // ---- 4. score[s] = Vrb + sum_k Vr[k] * tanh(dot(A[s,:], Ur[k,:]) + lm[k])
    //         Ur/Vr via constant AS -> s_load -> FMA with SGPR operand.
    cfloat* ur = to_const_as(Ur);
    cfloat* vr = to_const_as(Vr);
    cfloat* vrb = to_const_as(Vrb);
    float score = vrb[0];
    for (int k = 0; k < HH; ++k) {
        cfloat* urow = ur + k * HH;
        float4 c0 = make_float4(0.f, 0.f, 0.f, 0.f);
        float4 c1 = c0, c2 = c0, c3 = c0;
        KSTEP(0,  c0) KSTEP(1,  c1) KSTEP(2,  c2) KSTEP(3,  c3)
        KSTEP(4,  c0) KSTEP(5,  c1) KSTEP(6,  c2) KSTEP(7,  c3)
        KSTEP(8,  c0) KSTEP(9,  c1) KSTEP(10, c2) KSTEP(11, c3)
        KSTEP(12, c0) KSTEP(13, c1) KSTEP(14, c2) KSTEP(15, c3)
        KSTEP(16, c0) KSTEP(17, c1) KSTEP(18, c2) KSTEP(19, c3)
        KSTEP(20, c0) KSTEP(21, c1) KSTEP(22, c2) KSTEP(23, c3)
        KSTEP(24, c0) KSTEP(25, c1) KSTEP(26, c2) KSTEP(27, c3)
        KSTEP(28, c0) KSTEP(29, c1) KSTEP(30, c2) KSTEP(31, c3)
        float r0 = (c0.x + c0.y) + (c0.z + c0.w);
        float r1 = (c1.x + c1.y) + (c1.z + c1.w);
        float r2 = (c2.x + c2.y) + (c2.z + c2.w);
        float r3 = (c3.x + c3.y) + (c3.z + c3.w);
        float am = ((r0 + r1) + (r2 + r3)) + s_lm[k];
        score = fmaf(vr[k], fast_tanh(am), score);
    }

    if (s < SS && mask[b * SS + s]) score = -1e9f;

    // ---- 5. softmax over S within the block ----
    float v = (s < SS) ? score : -3.0e38f;
    #pragma unroll
    for (int off = 32; off > 0; off >>= 1)
        v = fmaxf(v, __shfl_down(v, off, 64));
    if (lane == 0) s_red[wv] = v;
    __syncthreads();   // fill stores long retired by now
    float m = fmaxf(fmaxf(s_red[0], s_red[1]), fmaxf(s_red[2], s_red[3]));

    float e = (s < SS) ? __expf(score - m) : 0.f;
    float sv = e;
    #pragma unroll
    for (int off = 32; off > 0; off >>= 1)
        sv += __shfl_down(sv, off, 64);
    if (lane == 0) s_red[4 + wv] = sv;
    __syncthreads();
    float tot = (s_red[4] + s_red[5]) + (s_red[6] + s_red[7]);

    // ---- 6. scatter-add (row private to block; in-row duplicate ids -> atomics)
    if (s < SS) {
        float att = e / tot;
        int idx = item_seq[b * SS + s];
        atomicAdd(out + (size_t)b * NI + idx, att);
    }
}

extern "C" void kernel_launch(void* const* d_in, const int* in_sizes, int n_in,
                              void* d_out, int out_size, void* d_ws, size_t ws_size,
                              hipStream_t stream) {
    const float* allm   = (const float*)d_in[0];
    const float* lastm  = (const float*)d_in[1];
    const int*   iseq   = (const int*)d_in[2];
    const unsigned char* mask = (const unsigned char*)d_in[3];
    const float* Ur     = (const float*)d_in[4];
    const float* Wr     = (const float*)d_in[5];
    const float* Vr     = (const float*)d_in[6];
    const float* Vrb    = (const float*)d_in[7];
    float* out          = (float*)d_out;

    rrd_fused_kernel<<<dim3(BB), dim3(256), 0, stream>>>(
        allm, lastm, iseq, mask, Ur, Wr, Vr, Vrb, out);
}

// Round 5
// 568.190 us; speedup vs baseline: 1.3056x; 1.3056x over previous
//
#include <hip/hip_runtime.h>
#include <math.h>
#include <stdint.h>

#define BB 1024
#define SS 200
#define HH 128
#define NI 100000

typedef __attribute__((ext_vector_type(8))) short short8;  // 8 bf16 (4 VGPRs)
typedef __attribute__((ext_vector_type(4))) float f32x4;   // MFMA C/D

// tanh(x) = sign(x) * (1 - e^{-2|x|}) / (1 + e^{-2|x|})
__device__ __forceinline__ float fast_tanh(float x) {
    float ax = fabsf(x);
    float t = __expf(-2.0f * ax);
    float r = (1.0f - t) / (1.0f + t);
    return copysignf(r, x);
}

// Split 8 consecutive fp32 into bf16 hi + bf16 lo (truncation split; residual
// captured exactly, dropped lo*lo term ~2^-16 relative).
__device__ __forceinline__ void split8(const float* __restrict__ p,
                                       short8& hi, short8& lo) {
    const float4* p4 = reinterpret_cast<const float4*>(p);
    float4 x0 = p4[0], x1 = p4[1];
    float v[8] = {x0.x, x0.y, x0.z, x0.w, x1.x, x1.y, x1.z, x1.w};
    #pragma unroll
    for (int j = 0; j < 8; ++j) {
        unsigned u = __float_as_uint(v[j]);
        unsigned short h = (unsigned short)(u >> 16);
        hi[j] = (short)h;
        float r = v[j] - __uint_as_float(((unsigned)h) << 16);
        lo[j] = (short)(__float_as_uint(r) >> 16);
    }
}

__global__ __launch_bounds__(256, 2)
void rrd_mfma_kernel(const float* __restrict__ allm,      // [B,S,H]
                     const float* __restrict__ lastm,     // [B,H]
                     const int* __restrict__ item_seq,    // [B,S]
                     const unsigned char* __restrict__ mask, // [B,S]
                     const float* __restrict__ Ur,        // [H,H]
                     const float* __restrict__ Wr,        // [H,H]
                     const float* __restrict__ Vr,        // [1,H]
                     const float* __restrict__ Vrb,       // [1]
                     float* __restrict__ out) {           // [B,N]
    const int b = blockIdx.x;
    const int tid = threadIdx.x;
    const int lane = tid & 63;
    const int w = tid >> 6;       // wave id: rows [64w, 64w+64)
    const int col = lane & 15;    // C col / B n / A m lane index
    const int quad = lane >> 4;   // k-quad (8 k each)

    __shared__ float s_last[HH];
    __shared__ float s_lm[HH];
    __shared__ float s_vr[HH];
    __shared__ float s_score[256];
    __shared__ float s_red[8];

    // ---- stage last_memory + Vr into LDS ----
    if (tid < HH) s_last[tid] = lastm[b * HH + tid];
    else          s_vr[tid - HH] = Vr[tid - HH];
    __syncthreads();

    // ---- lm[k] = sum_h last[b,h] * Wr[k,h] ----
    if (tid < HH) {
        const float4* wrow = reinterpret_cast<const float4*>(Wr + tid * HH);
        const float4* lrow = reinterpret_cast<const float4*>(s_last);
        float4 acc = make_float4(0.f, 0.f, 0.f, 0.f);
        #pragma unroll
        for (int i = 0; i < HH / 4; ++i) {
            float4 wv = wrow[i];
            float4 lv = lrow[i];
            acc.x = fmaf(lv.x, wv.x, acc.x);
            acc.y = fmaf(lv.y, wv.y, acc.y);
            acc.z = fmaf(lv.z, wv.z, acc.z);
            acc.w = fmaf(lv.w, wv.w, acc.w);
        }
        s_lm[tid] = (acc.x + acc.y) + (acc.z + acc.w);
    }
    __syncthreads();   // s_lm/s_vr ready for epilogue

    // ---- MFMA main: am[s,k] = A[s,:] . Ur[k,:], split-bf16 3-term ----
    // 2 passes x 2 m-tiles; all 8 n-tiles (128 k-outputs) accumulated.
    const int row0 = w * 64;
    #pragma unroll 1
    for (int p = 0; p < 2; ++p) {
        f32x4 C[2][8] = {};   // fp32 accum, fresh per pass
        #pragma unroll 1
        for (int c = 0; c < 4; ++c) {      // K chunks of 32
            short8 Bh[8], Bl[8];
            #pragma unroll
            for (int n = 0; n < 8; ++n) {  // B frag: Ur[n*16+col][c*32+quad*8 ..+7]
                const float* bp = Ur + (size_t)(n * 16 + col) * HH + c * 32 + quad * 8;
                split8(bp, Bh[n], Bl[n]);
            }
            #pragma unroll
            for (int t = 0; t < 2; ++t) {
                int row = row0 + (p * 2 + t) * 16 + col;
                if (row > SS - 1) row = SS - 1;   // clamp: pad rows read real data
                const float* ap = allm + ((size_t)b * SS + row) * HH + c * 32 + quad * 8;
                short8 Ah, Al;
                split8(ap, Ah, Al);
                #pragma unroll
                for (int n = 0; n < 8; ++n) {
                    C[t][n] = __builtin_amdgcn_mfma_f32_16x16x32_bf16(Ah, Bh[n], C[t][n], 0, 0, 0);
                    C[t][n] = __builtin_amdgcn_mfma_f32_16x16x32_bf16(Ah, Bl[n], C[t][n], 0, 0, 0);
                    C[t][n] = __builtin_amdgcn_mfma_f32_16x16x32_bf16(Al, Bh[n], C[t][n], 0, 0, 0);
                }
            }
        }
        // ---- epilogue in C layout: col=lane&15, row=quad*4+reg ----
        #pragma unroll
        for (int t = 0; t < 2; ++t) {
            float a0 = 0.f, a1 = 0.f, a2 = 0.f, a3 = 0.f;
            #pragma unroll
            for (int n = 0; n < 8; ++n) {
                float lmc = s_lm[n * 16 + col];
                float vrc = s_vr[n * 16 + col];
                a0 = fmaf(vrc, fast_tanh(C[t][n][0] + lmc), a0);
                a1 = fmaf(vrc, fast_tanh(C[t][n][1] + lmc), a1);
                a2 = fmaf(vrc, fast_tanh(C[t][n][2] + lmc), a2);
                a3 = fmaf(vrc, fast_tanh(C[t][n][3] + lmc), a3);
            }
            #pragma unroll
            for (int off = 1; off < 16; off <<= 1) {
                a0 += __shfl_xor(a0, off, 64);
                a1 += __shfl_xor(a1, off, 64);
                a2 += __shfl_xor(a2, off, 64);
                a3 += __shfl_xor(a3, off, 64);
            }
            if (col == 0) {
                int rb = row0 + (p * 2 + t) * 16 + quad * 4;
                s_score[rb + 0] = a0;
                s_score[rb + 1] = a1;
                s_score[rb + 2] = a2;
                s_score[rb + 3] = a3;
            }
        }
    }

    // ---- zero-fill this batch's output row (AFTER mfma loads: stores don't
    //      block the k-loop's vmcnt waits; drained at the next barrier) ----
    {
        float4* orow = reinterpret_cast<float4*>(out + (size_t)b * NI);
        const float4 z4 = make_float4(0.f, 0.f, 0.f, 0.f);
        for (int i = tid; i < NI / 4; i += 256) orow[i] = z4;
    }

    __syncthreads();   // s_score visible; fill stores drained to L2

    // ---- softmax over S ----
    const int s = tid;
    float score = s_score[s] + Vrb[0];
    if (s < SS && mask[b * SS + s]) score = -1e9f;

    float v = (s < SS) ? score : -3.0e38f;
    #pragma unroll
    for (int off = 32; off > 0; off >>= 1)
        v = fmaxf(v, __shfl_down(v, off, 64));
    if (lane == 0) s_red[w] = v;
    __syncthreads();
    float m = fmaxf(fmaxf(s_red[0], s_red[1]), fmaxf(s_red[2], s_red[3]));

    float e = (s < SS) ? __expf(score - m) : 0.f;
    float sv = e;
    #pragma unroll
    for (int off = 32; off > 0; off >>= 1)
        sv += __shfl_down(sv, off, 64);
    if (lane == 0) s_red[4 + w] = sv;
    __syncthreads();
    float tot = (s_red[4] + s_red[5]) + (s_red[6] + s_red[7]);

    // ---- scatter-add (row private to block; in-row duplicate ids -> atomics)
    if (s < SS) {
        float att = e / tot;
        int idx = item_seq[b * SS + s];
        atomicAdd(out + (size_t)b * NI + idx, att);
    }
}

extern "C" void kernel_launch(void* const* d_in, const int* in_sizes, int n_in,
                              void* d_out, int out_size, void* d_ws, size_t ws_size,
                              hipStream_t stream) {
    const float* allm   = (const float*)d_in[0];
    const float* lastm  = (const float*)d_in[1];
    const int*   iseq   = (const int*)d_in[2];
    const unsigned char* mask = (const unsigned char*)d_in[3];
    const float* Ur     = (const float*)d_in[4];
    const float* Wr     = (const float*)d_in[5];
    const float* Vr     = (const float*)d_in[6];
    const float* Vrb    = (const float*)d_in[7];
    float* out          = (float*)d_out;

    rrd_mfma_kernel<<<dim3(BB), dim3(256), 0, stream>>>(
        allm, lastm, iseq, mask, Ur, Wr, Vr, Vrb, out);
}